// Round 4
// baseline (31.688 us; speedup 1.0000x reference)
//
#include <hip/hip_runtime.h>

// Problem constants (from reference setup_inputs)
constexpr int B    = 2;
constexpr int CIN  = 64;
constexpr int N    = 128;
constexpr int T    = 24;
constexpr int HID  = 64;
constexpr int COUT = 64;
constexpr int NT   = N * T;        // 3072
constexpr int ROWS = B * N * T;    // 6144
constexpr int MLP_BLOCKS = ROWS / 4;   // 1536
constexpr int TRS_BLOCKS = B * N;      // 256

// ---------------------------------------------------------------------------
// Kernel 1 "prep": MLP rows (blocks [0,1536)) + att transpose (blocks
// [1536,1792)).
//  MLP: h = x_row@W1+b1 ; mvb2 = h@W2[:HID]+b2 ; mh = h@W2[HID:]
//       stored [b][t][n][c] (coalesced writes, lane=c).
//  Transpose: att[b,0,i,j,t] -> att_T[b][t][i][j]; per block (b,i):
//       read 12 KB flat-contiguous, write 24 chunks of 512 B. LDS [128][25].
// ---------------------------------------------------------------------------
__global__ __launch_bounds__(256) void k_prep(
    const float* __restrict__ x,
    const float* __restrict__ att,
    const float* __restrict__ W1,
    const float* __restrict__ b1,
    const float* __restrict__ W2,
    const float* __restrict__ b2,
    float* __restrict__ mvb2,
    float* __restrict__ mh,
    float* __restrict__ attT)
{
    const int tid = threadIdx.x;

    if (blockIdx.x < MLP_BLOCKS) {
        __shared__ float xs[4][64];
        __shared__ float hs[4][64];

        const int r   = tid >> 6;
        const int k   = tid & 63;
        const int row = blockIdx.x * 4 + r;
        const int b   = row / NT;
        const int nt  = row - b * NT;

        xs[r][k] = x[(size_t)b * CIN * NT + (size_t)k * NT + nt];
        __syncthreads();

        float h = b1[k];
#pragma unroll
        for (int c = 0; c < CIN; ++c) {
            h += xs[r][c] * W1[c * HID + k];
        }
        hs[r][k] = h;
        __syncthreads();

        float mv = 0.f, mhv = 0.f;
#pragma unroll
        for (int q = 0; q < HID; ++q) {
            const float hq = hs[r][q];
            mv  += hq * W2[q * COUT + k];
            mhv += hq * W2[(HID + q) * COUT + k];
        }

        const int n = nt / T;
        const int t = nt - n * T;
        const int o = ((b * T + t) * N + n) * COUT + k;
        mvb2[o] = mv + b2[k];
        mh[o]   = mhv;
    } else {
        // --- att transpose block ---
        __shared__ float ts[N][T + 1];   // [j][t], pad to 25 banks

        const int tb = blockIdx.x - MLP_BLOCKS;   // (b,i)
        const int b  = tb >> 7;
        const int i  = tb & 127;

        const float* ab = att + ((size_t)b * N + i) * NT;   // flat [j*T + t]
#pragma unroll
        for (int u = 0; u < 12; ++u) {
            const int idx = tid + 256 * u;       // = j*T + t
            const int j   = idx / T;
            const int t   = idx - j * T;
            ts[j][t] = ab[idx];                  // coalesced read
        }
        __syncthreads();
#pragma unroll
        for (int u = 0; u < 12; ++u) {
            const int idx = tid + 256 * u;
            const int t   = idx >> 7;            // 0..23
            const int j   = idx & 127;
            attT[((size_t)(b * T + t) * N + i) * N + j] = ts[j][t];  // coalesced write
        }
    }
}

// ---------------------------------------------------------------------------
// Kernel 2: attention aggregation, fully coalesced.
//   Block = (bt, itile of 16 i-rows).
//   Stage: mhs[128][64] (32 KB, contiguous) + as_[16][128] (8 KB, contiguous
//   slab of att_T). j-loop pure LDS. Store upd to upd_ws[bt][i][c], lane=c
//   coalesced. (Final (b,c,i,t) layout produced by k_out.)
// ---------------------------------------------------------------------------
__global__ __launch_bounds__(256) void k_att(
    const float* __restrict__ attT,
    const float* __restrict__ mvb2,
    const float* __restrict__ mh,
    float* __restrict__ upd_ws)
{
    __shared__ float mhs[N][COUT];   // 32 KB
    __shared__ float as_[16][N];     // 8 KB

    const int blk   = blockIdx.x;
    const int itile = blk & 7;
    const int bt    = blk >> 3;
    const int tid   = threadIdx.x;
    const int w     = tid >> 6;
    const int lane  = tid & 63;

    // Stage mh panel (contiguous 32 KB).
    {
        const float4* src = (const float4*)(mh + (size_t)bt * N * COUT);
        float4*       dst = (float4*)(&mhs[0][0]);
#pragma unroll
        for (int u = 0; u < 8; ++u) {
            dst[tid + 256 * u] = src[tid + 256 * u];
        }
    }
    // Stage att tile (contiguous 8 KB slab of att_T).
    {
        const float4* src = (const float4*)(attT + ((size_t)bt * N + itile * 16) * N);
        float4*       dst = (float4*)(&as_[0][0]);
#pragma unroll
        for (int u = 0; u < 2; ++u) {
            dst[tid + 256 * u] = src[tid + 256 * u];
        }
    }
    __syncthreads();

    const int c  = lane;
    const int r0 = w * 4;

    float acc0 = 0.f, acc1 = 0.f, acc2 = 0.f, acc3 = 0.f;
    float s0 = 0.f, s1 = 0.f, s2 = 0.f, s3 = 0.f;

#pragma unroll 4
    for (int j = 0; j < N; j += 4) {
        const float4 a0 = *(const float4*)&as_[r0 + 0][j];
        const float4 a1 = *(const float4*)&as_[r0 + 1][j];
        const float4 a2 = *(const float4*)&as_[r0 + 2][j];
        const float4 a3 = *(const float4*)&as_[r0 + 3][j];
        const float m0 = mhs[j + 0][c];
        const float m1 = mhs[j + 1][c];
        const float m2 = mhs[j + 2][c];
        const float m3 = mhs[j + 3][c];

        acc0 += a0.x * m0 + a0.y * m1 + a0.z * m2 + a0.w * m3;
        acc1 += a1.x * m0 + a1.y * m1 + a1.z * m2 + a1.w * m3;
        acc2 += a2.x * m0 + a2.y * m1 + a2.z * m2 + a2.w * m3;
        acc3 += a3.x * m0 + a3.y * m1 + a3.z * m2 + a3.w * m3;
        s0 += a0.x + a0.y + a0.z + a0.w;
        s1 += a1.x + a1.y + a1.z + a1.w;
        s2 += a2.x + a2.y + a2.z + a2.w;
        s3 += a3.x + a3.y + a3.z + a3.w;
    }

    // Epilogue: upd_ws[bt][i][c] — coalesced.
    const int ibase = itile * 16 + r0;
    const float* mb = mvb2  + ((size_t)bt * N + ibase) * COUT + c;
    float*       ub = upd_ws + ((size_t)bt * N + ibase) * COUT + c;
    ub[0 * COUT] = s0 * mb[0 * COUT] + acc0;
    ub[1 * COUT] = s1 * mb[1 * COUT] + acc1;
    ub[2 * COUT] = s2 * mb[2 * COUT] + acc2;
    ub[3 * COUT] = s3 * mb[3 * COUT] + acc3;
}

// ---------------------------------------------------------------------------
// Kernel 3: output transpose upd_ws[b][t][i][c] -> out[b][c][i][t].
//   Block = (b,i); LDS tile [24][65]. Reads 256-float contiguous chunks,
//   writes 96 B contiguous per c-row.
// ---------------------------------------------------------------------------
__global__ __launch_bounds__(256) void k_out(
    const float* __restrict__ upd_ws,
    float* __restrict__ out)
{
    __shared__ float ts[T][COUT + 1];

    const int tid = threadIdx.x;
    const int b   = blockIdx.x >> 7;
    const int i   = blockIdx.x & 127;

#pragma unroll
    for (int u = 0; u < 6; ++u) {
        const int idx = tid + 256 * u;           // t*64 + c
        const int t   = idx >> 6;
        const int c   = idx & 63;
        ts[t][c] = upd_ws[((size_t)(b * T + t) * N + i) * COUT + c];
    }
    __syncthreads();
#pragma unroll
    for (int u = 0; u < 6; ++u) {
        const int idx = tid + 256 * u;           // c*24 + t
        const int c   = idx / T;
        const int t   = idx - c * T;
        out[((size_t)(b * COUT + c) * N + i) * T + t] = ts[t][c];
    }
}

// ---------------------------------------------------------------------------
extern "C" void kernel_launch(void* const* d_in, const int* in_sizes, int n_in,
                              void* d_out, int out_size, void* d_ws, size_t ws_size,
                              hipStream_t stream)
{
    const float* x   = (const float*)d_in[0];
    const float* att = (const float*)d_in[1];
    const float* W1  = (const float*)d_in[2];
    const float* b1  = (const float*)d_in[3];
    const float* W2  = (const float*)d_in[4];
    const float* b2  = (const float*)d_in[5];
    float* out = (float*)d_out;

    float* mvb2 = (float*)d_ws;                       // ROWS*COUT
    float* mhws = mvb2 + (size_t)ROWS * COUT;         // ROWS*COUT
    float* attT = mhws + (size_t)ROWS * COUT;         // B*T*N*N
    float* upd  = attT + (size_t)B * T * N * N;       // ROWS*COUT

    k_prep<<<MLP_BLOCKS + TRS_BLOCKS, 256, 0, stream>>>(x, att, W1, b1, W2, b2,
                                                        mvb2, mhws, attT);
    k_att<<<B * T * 8, 256, 0, stream>>>(attT, mvb2, mhws, upd);
    k_out<<<B * N, 256, 0, stream>>>(upd, out);
}

// Round 6
// 26.755 us; speedup vs baseline: 1.1844x; 1.1844x over previous
//
#include <hip/hip_runtime.h>

// Problem constants (from reference setup_inputs)
constexpr int B_   = 2;
constexpr int CIN  = 64;
constexpr int N    = 128;
constexpr int T    = 24;
constexpr int HID  = 64;
constexpr int COUT = 64;
constexpr int NT   = N * T;            // 3072
constexpr int ROWS = B_ * N * T;       // 6144
constexpr int BT   = B_ * T;           // 48
constexpr int MLP_BLOCKS = ROWS / 4;   // 1536
constexpr int TRS_BLOCKS = B_ * N;     // 256

typedef __attribute__((ext_vector_type(8))) short short8;  // 8 bf16 = MFMA A/B frag
typedef __attribute__((ext_vector_type(4))) float f32x4;

// float -> bf16 bits, round-to-nearest-even
__device__ inline unsigned short f2bf(float f) {
    unsigned u = __float_as_uint(f);
    return (unsigned short)((u + 0x7FFFu + ((u >> 16) & 1u)) >> 16);
}

// ---------------------------------------------------------------------------
// k_prep: MLP blocks [0,1536) + att transpose/sum blocks [1536,1792).
//  MLP (4 rows/block): h = x_row@W1+b1; writes
//    mvb2T[bt][c][n] = h@W2[:HID]+b2   (f32, scattered store)
//    mhT  [bt][c][n] = bf16(h@W2[HID:])(scattered 2B store)
//  Transpose (block=(b,i)): att[b,0,i,j,t] -> attTb[bt][i][j] bf16 (packed
//    u32 coalesced writes) + asum_g[bt][i] = sum_j (f32).
// ---------------------------------------------------------------------------
__global__ __launch_bounds__(256) void k_prep(
    const float* __restrict__ x,
    const float* __restrict__ att,
    const float* __restrict__ W1,
    const float* __restrict__ b1,
    const float* __restrict__ W2,
    const float* __restrict__ b2,
    float* __restrict__ mvb2T,
    unsigned short* __restrict__ mhT,
    unsigned int* __restrict__ attTb32,   // attTb as packed u32 pairs
    float* __restrict__ asum_g)
{
    const int tid = threadIdx.x;

    if (blockIdx.x < MLP_BLOCKS) {
        __shared__ float xs[4][64];
        __shared__ float hs[4][64];

        const int r   = tid >> 6;
        const int k   = tid & 63;
        const int row = blockIdx.x * 4 + r;
        const int b   = row / NT;
        const int nt  = row - b * NT;

        xs[r][k] = x[(size_t)b * CIN * NT + (size_t)k * NT + nt];
        __syncthreads();

        float h = b1[k];
#pragma unroll
        for (int c = 0; c < CIN; ++c) h += xs[r][c] * W1[c * HID + k];
        hs[r][k] = h;
        __syncthreads();

        float mv = 0.f, mhv = 0.f;
#pragma unroll
        for (int q = 0; q < HID; ++q) {
            const float hq = hs[r][q];
            mv  += hq * W2[q * COUT + k];
            mhv += hq * W2[(HID + q) * COUT + k];
        }
        const int n  = nt / T;
        const int t  = nt - n * T;
        const int bt = b * T + t;
        mvb2T[((size_t)bt * COUT + k) * N + n] = mv + b2[k];
        mhT  [((size_t)bt * COUT + k) * N + n] = f2bf(mhv);
    } else {
        __shared__ float ts[N][T + 1];   // [j][t]
        __shared__ float psum[T][8];

        const int tb = blockIdx.x - MLP_BLOCKS;   // (b,i)
        const int b  = tb >> 7;
        const int i  = tb & 127;

        const float* ab = att + ((size_t)b * N + i) * NT;   // flat [j*T+t]
#pragma unroll
        for (int u = 0; u < 12; ++u) {
            const int idx = tid + 256 * u;
            const int j   = idx / T;
            const int t   = idx - j * T;
            ts[j][t] = ab[idx];          // coalesced read
        }
        __syncthreads();

        // attTb[bt][i][j] bf16, written as packed u32 (coalesced).
#pragma unroll
        for (int u = 0; u < 6; ++u) {
            const int e2 = tid + 256 * u;     // pair index, 0..1535
            const int t  = e2 >> 6;           // 0..23
            const int jp = e2 & 63;           // j pair
            const int j  = jp * 2;
            const unsigned pk = (unsigned)f2bf(ts[j][t])
                              | ((unsigned)f2bf(ts[j + 1][t]) << 16);
            attTb32[((size_t)(b * T + t) * N + i) * 64 + jp] = pk;
        }
        // asum_g[bt][i] = sum_j att (fp32 — keeps dominant term exact)
        if (tid < 192) {
            const int t = tid >> 3;
            const int p = tid & 7;
            float s = 0.f;
#pragma unroll
            for (int q = 0; q < 16; ++q) s += ts[p * 16 + q][t];
            psum[t][p] = s;
        }
        __syncthreads();
        if (tid < T) {
            float s = 0.f;
#pragma unroll
            for (int p = 0; p < 8; ++p) s += psum[tid][p];
            asum_g[(size_t)(b * T + tid) * N + i] = s;
        }
    }
}

// ---------------------------------------------------------------------------
// k_att: pure-MFMA einsum, NO LDS, no syncthreads.
//   Block = (bt, itile); wave w owns c-tile n0=w*16.
//   D(16x16) = attTb_tile(16x128) @ mhT^T(128x16) via 4x mfma 16x16x32 bf16.
//   A-frag: lane reads attTb[bt][itile*16 + (lane&15)][k-slice] (16B contig).
//   B-frag: lane reads mhT[bt][n0 + (lane&15)][k-slice]        (16B contig).
//   Same k-mapping on both operands -> permutation cancels in contraction.
//   C/D: col=lane&15, row=(lane>>4)*4+reg (m89-verified).
//   Epilogue: out[b][c][i][t] = acc[e] + asum[i] * mvb2T[bt][c][i].
// ---------------------------------------------------------------------------
__global__ __launch_bounds__(256) void k_att(
    const unsigned short* __restrict__ attTb,
    const unsigned short* __restrict__ mhT,
    const float* __restrict__ mvb2T,
    const float* __restrict__ asum_g,
    float* __restrict__ out)
{
    const int blk   = blockIdx.x;
    const int itile = blk & 7;
    const int bt    = blk >> 3;
    const int b     = bt / T;
    const int t     = bt - b * T;

    const int tid  = threadIdx.x;
    const int w    = tid >> 6;
    const int lane = tid & 63;
    const int c16  = lane & 15;
    const int q4   = lane >> 4;
    const int n0   = w * 16;

    const unsigned short* arow = attTb + ((size_t)bt * N + itile * 16 + c16) * N;
    const unsigned short* brow = mhT   + ((size_t)bt * COUT + n0 + c16) * N;

    f32x4 acc = {0.f, 0.f, 0.f, 0.f};
#pragma unroll
    for (int ks = 0; ks < 4; ++ks) {
        const short8 a  = *(const short8*)(arow + ks * 32 + q4 * 8);
        const short8 bb = *(const short8*)(brow + ks * 32 + q4 * 8);
        acc = __builtin_amdgcn_mfma_f32_16x16x32_bf16(a, bb, acc, 0, 0, 0);
    }

    const int il0 = itile * 16 + q4 * 4;   // first of this thread's 4 i-rows
    const int cc  = n0 + c16;

    const f32x4 mb  = *(const f32x4*)(mvb2T + ((size_t)bt * COUT + cc) * N + il0);
    const f32x4 as4 = *(const f32x4*)(asum_g + (size_t)bt * N + il0);

    float* ob = out + (((size_t)b * COUT + cc) * N + il0) * T + t;
#pragma unroll
    for (int e = 0; e < 4; ++e) {
        ob[e * T] = acc[e] + as4[e] * mb[e];
    }
}

// ---------------------------------------------------------------------------
extern "C" void kernel_launch(void* const* d_in, const int* in_sizes, int n_in,
                              void* d_out, int out_size, void* d_ws, size_t ws_size,
                              hipStream_t stream)
{
    const float* x   = (const float*)d_in[0];
    const float* att = (const float*)d_in[1];
    const float* W1  = (const float*)d_in[2];
    const float* b1  = (const float*)d_in[3];
    const float* W2  = (const float*)d_in[4];
    const float* b2  = (const float*)d_in[5];
    float* out = (float*)d_out;

    // Workspace layout (bytes), all 16B-aligned:
    char* ws = (char*)d_ws;
    float*          mvb2T   = (float*)ws;                          // 1,572,864 B
    float*          asum_g  = (float*)(ws + 1572864);              //    24,576 B
    unsigned short* mhT     = (unsigned short*)(ws + 1597440);     //   786,432 B
    unsigned short* attTb   = (unsigned short*)(ws + 2383872);     // 1,572,864 B
    unsigned int*   attTb32 = (unsigned int*)attTb;

    k_prep<<<MLP_BLOCKS + TRS_BLOCKS, 256, 0, stream>>>(
        x, att, W1, b1, W2, b2, mvb2T, mhT, attTb32, asum_g);
    k_att<<<BT * 8, 256, 0, stream>>>(attTb, mhT, mvb2T, asum_g, out);
}